// Round 5
// baseline (251.570 us; speedup 1.0000x reference)
//
#include <hip/hip_runtime.h>
#include <stdint.h>

// ---------------------------------------------------------------------------
// Bit-exact replica of XLA:CPU's f32 exp (GenerateVF32Exp, Cephes/Eigen pexp)
// as compiled with TargetOptions.AllowFPOpFusion == Fast (x86 FMA fusion).
// gfx950 v_fma_f32 == x86 vfmadd (IEEE single rounding). VERIFIED bit-exact
// in rounds 3/4 (absmax 0.0) — do not modify.
// ---------------------------------------------------------------------------
__device__ __forceinline__ float xla_cpu_expf_fused(float x) {
#pragma clang fp contract(off)
  const float exp_hi = 88.3762626647950f;
  const float exp_lo = -88.3762626647949f;
  const float log2ef = 1.44269504088896341f;
  const float c1 = 0.693359375f;
  const float c2 = -2.12194440e-4f;
  const float p0 = 1.9875691500e-4f;
  const float p1 = 1.3981999507e-3f;
  const float p2 = 8.3334519073e-3f;
  const float p3 = 4.1665795894e-2f;
  const float p4 = 1.6666665459e-1f;
  const float p5 = 5.0000001201e-1f;

  float xc = fminf(fmaxf(x, exp_lo), exp_hi);
  float fx = floorf(__builtin_fmaf(xc, log2ef, 0.5f));
  float xr = __builtin_fmaf(-c1, fx, xc);
  xr = __builtin_fmaf(-c2, fx, xr);

  float z2 = xr * xr;
  float y = __builtin_fmaf(xr, p0, p1);
  y = __builtin_fmaf(y, xr, p2);
  y = __builtin_fmaf(y, xr, p3);
  y = __builtin_fmaf(y, xr, p4);
  y = __builtin_fmaf(y, xr, p5);
  y = __builtin_fmaf(y, z2, xr);
  y = 1.0f + y;

  int n = (int)fx;
  float p2n = __int_as_float((n + 127) << 23);
  float res = y * p2n;
  return fmaxf(res, x);
}

__device__ __forceinline__ float silu_ref(float v) {
#pragma clang fp contract(off)
  float t = xla_cpu_expf_fused(-v);
  float s = 1.0f / (1.0f + t);   // IEEE correctly-rounded divide
  return v * s;
}

typedef uint32_t u32x4 __attribute__((ext_vector_type(4)));

// Per-uint4 pulse work: pack nibble -> 8-lane OR-butterfly -> silu -> unpack.
// Each aligned 8-lane group owns one value; silu computed redundantly x8
// (VALU ~11% busy -> free). sh = 28 - 4*(lane&7).
__device__ __forceinline__ u32x4 process4(u32x4 w, int sh) {
  uint32_t nib = ((w[0] != 0u) ? 8u : 0u) | ((w[1] != 0u) ? 4u : 0u) |
                 ((w[2] != 0u) ? 2u : 0u) | ((w[3] != 0u) ? 1u : 0u);
  uint32_t u = nib << sh;
  u |= (uint32_t)__shfl_xor((int)u, 1);
  u |= (uint32_t)__shfl_xor((int)u, 2);
  u |= (uint32_t)__shfl_xor((int)u, 4);

  const float v = __uint_as_float(u);
  const uint32_t ru = __float_as_uint(silu_ref(v));

  const uint32_t nib4 = (ru >> sh) & 0xFu;
  u32x4 o;
  o[0] = (nib4 & 8u) ? 0x3F800000u : 0u;
  o[1] = (nib4 & 4u) ? 0x3F800000u : 0u;
  o[2] = (nib4 & 2u) ? 0x3F800000u : 0u;
  o[3] = (nib4 & 1u) ? 0x3F800000u : 0u;
  return o;
}

// Coalesced + 4x unrolled: lane L loads uint4 (base+L) so each wave covers
// 1 KB contiguous per load instruction; 4 independent chains per thread give
// 4x memory-level parallelism. Nontemporal hints: both streams are touched
// exactly once (537 MB each >> 32 MB L2) — don't pollute L2.
__global__ __launch_bounds__(256) void spike_silu_kernel(
    const u32x4* __restrict__ in, u32x4* __restrict__ out, int n4) {
  const int stride = gridDim.x * blockDim.x;
  const int sh = 28 - 4 * (threadIdx.x & 7);
  int i = blockIdx.x * blockDim.x + threadIdx.x;

  for (; i + 3 * stride < n4; i += 4 * stride) {
    u32x4 w0 = __builtin_nontemporal_load(&in[i]);
    u32x4 w1 = __builtin_nontemporal_load(&in[i + stride]);
    u32x4 w2 = __builtin_nontemporal_load(&in[i + 2 * stride]);
    u32x4 w3 = __builtin_nontemporal_load(&in[i + 3 * stride]);

    u32x4 o0 = process4(w0, sh);
    u32x4 o1 = process4(w1, sh);
    u32x4 o2 = process4(w2, sh);
    u32x4 o3 = process4(w3, sh);

    __builtin_nontemporal_store(o0, &out[i]);
    __builtin_nontemporal_store(o1, &out[i + stride]);
    __builtin_nontemporal_store(o2, &out[i + 2 * stride]);
    __builtin_nontemporal_store(o3, &out[i + 3 * stride]);
  }
  for (; i < n4; i += stride) {
    u32x4 w = __builtin_nontemporal_load(&in[i]);
    u32x4 o = process4(w, sh);
    __builtin_nontemporal_store(o, &out[i]);
  }
}

extern "C" void kernel_launch(void* const* d_in, const int* in_sizes, int n_in,
                              void* d_out, int out_size, void* d_ws, size_t ws_size,
                              hipStream_t stream) {
  (void)in_sizes; (void)n_in; (void)d_ws; (void)ws_size;
  const u32x4* in = reinterpret_cast<const u32x4*>(d_in[0]);
  u32x4* out = reinterpret_cast<u32x4*>(d_out);
  const int n4 = out_size / 4;  // 33,554,432 uint4s (16 B each)

  const int threads = 256;
  const int blocks = 2048;  // 8 blocks/CU exactly; 64 iters/thread = 16 unrolled
  spike_silu_kernel<<<blocks, threads, 0, stream>>>(in, out, n4);
}

// Round 6
// 200.268 us; speedup vs baseline: 1.2562x; 1.2562x over previous
//
#include <hip/hip_runtime.h>
#include <stdint.h>

// ---------------------------------------------------------------------------
// Bit-exact replica of XLA:CPU's f32 exp (GenerateVF32Exp, Cephes/Eigen pexp)
// as compiled with TargetOptions.AllowFPOpFusion == Fast (x86 FMA fusion).
// gfx950 v_fma_f32 == x86 vfmadd (IEEE single rounding). VERIFIED bit-exact
// in rounds 3/4/5 (absmax 0.0) — do not modify.
// ---------------------------------------------------------------------------
__device__ __forceinline__ float xla_cpu_expf_fused(float x) {
#pragma clang fp contract(off)
  const float exp_hi = 88.3762626647950f;
  const float exp_lo = -88.3762626647949f;
  const float log2ef = 1.44269504088896341f;
  const float c1 = 0.693359375f;
  const float c2 = -2.12194440e-4f;
  const float p0 = 1.9875691500e-4f;
  const float p1 = 1.3981999507e-3f;
  const float p2 = 8.3334519073e-3f;
  const float p3 = 4.1665795894e-2f;
  const float p4 = 1.6666665459e-1f;
  const float p5 = 5.0000001201e-1f;

  float xc = fminf(fmaxf(x, exp_lo), exp_hi);
  float fx = floorf(__builtin_fmaf(xc, log2ef, 0.5f));
  float xr = __builtin_fmaf(-c1, fx, xc);
  xr = __builtin_fmaf(-c2, fx, xr);

  float z2 = xr * xr;
  float y = __builtin_fmaf(xr, p0, p1);
  y = __builtin_fmaf(y, xr, p2);
  y = __builtin_fmaf(y, xr, p3);
  y = __builtin_fmaf(y, xr, p4);
  y = __builtin_fmaf(y, xr, p5);
  y = __builtin_fmaf(y, z2, xr);
  y = 1.0f + y;

  int n = (int)fx;
  float p2n = __int_as_float((n + 127) << 23);
  float res = y * p2n;
  return fmaxf(res, x);
}

__device__ __forceinline__ float silu_ref(float v) {
#pragma clang fp contract(off)
  float t = xla_cpu_expf_fused(-v);
  float s = 1.0f / (1.0f + t);   // IEEE correctly-rounded divide
  return v * s;
}

typedef uint32_t u32x4 __attribute__((ext_vector_type(4)));

// Per-uint4 pulse work: pack nibble -> 8-lane OR-butterfly -> silu -> unpack.
// Each aligned 8-lane group owns one value; silu computed redundantly x8
// (VALU ~10% busy -> free). sh = 28 - 4*(lane&7).
__device__ __forceinline__ u32x4 process4(u32x4 w, int sh) {
  uint32_t nib = ((w[0] != 0u) ? 8u : 0u) | ((w[1] != 0u) ? 4u : 0u) |
                 ((w[2] != 0u) ? 2u : 0u) | ((w[3] != 0u) ? 1u : 0u);
  uint32_t u = nib << sh;
  u |= (uint32_t)__shfl_xor((int)u, 1);
  u |= (uint32_t)__shfl_xor((int)u, 2);
  u |= (uint32_t)__shfl_xor((int)u, 4);

  const float v = __uint_as_float(u);
  const uint32_t ru = __float_as_uint(silu_ref(v));

  const uint32_t nib4 = (ru >> sh) & 0xFu;
  u32x4 o;
  o[0] = (nib4 & 8u) ? 0x3F800000u : 0u;
  o[1] = (nib4 & 4u) ? 0x3F800000u : 0u;
  o[2] = (nib4 & 2u) ? 0x3F800000u : 0u;
  o[3] = (nib4 & 1u) ? 0x3F800000u : 0u;
  return o;
}

// Coalesced + 4-deep MLP, occupancy-pinned:
//  - lane L loads uint4 (base + L): each wave covers 1 KB contiguous/instr.
//  - 4 loads per thread at offsets j*blockDim (block spans 16 KB contiguous),
//    issued back-to-back -> 4 outstanding VMEM ops per wave (vmcnt(3..0)),
//    then processed+stored SEQUENTIALLY to keep the live set small.
//  - __launch_bounds__(256, 8): pin 8 waves/SIMD -> allocator must stay
//    <=64 VGPR (round-5 lesson: unpinned 4-chain interleave blew past 64
//    and halved occupancy -> 208->251us regression).
//  - no nontemporal hints (second round-5 variable, removed).
__global__ __launch_bounds__(256, 8) void spike_silu_kernel(
    const u32x4* __restrict__ in, u32x4* __restrict__ out, int n4) {
  const int bdim = blockDim.x;                      // 256
  const int stride4 = gridDim.x * bdim * 4;
  const int sh = 28 - 4 * (threadIdx.x & 7);
  int i0 = blockIdx.x * bdim * 4 + threadIdx.x;

  for (; i0 + 3 * bdim < n4; i0 += stride4) {
    // 4 independent loads in flight
    u32x4 w0 = in[i0];
    u32x4 w1 = in[i0 + bdim];
    u32x4 w2 = in[i0 + 2 * bdim];
    u32x4 w3 = in[i0 + 3 * bdim];

    // sequential process+store: peak live ~ 3 pending loads + 1 workset
    out[i0] = process4(w0, sh);
    out[i0 + bdim] = process4(w1, sh);
    out[i0 + 2 * bdim] = process4(w2, sh);
    out[i0 + 3 * bdim] = process4(w3, sh);
  }
  // tail (does not execute for n4 = 2^25: 16 exact sweeps) — kept for safety
  for (; i0 < n4; i0 += bdim) {
    out[i0] = process4(in[i0], sh);
  }
}

extern "C" void kernel_launch(void* const* d_in, const int* in_sizes, int n_in,
                              void* d_out, int out_size, void* d_ws, size_t ws_size,
                              hipStream_t stream) {
  (void)in_sizes; (void)n_in; (void)d_ws; (void)ws_size;
  const u32x4* in = reinterpret_cast<const u32x4*>(d_in[0]);
  u32x4* out = reinterpret_cast<u32x4*>(d_out);
  const int n4 = out_size / 4;  // 33,554,432 uint4s (16 B each)

  const int threads = 256;
  const int blocks = 2048;  // 16 sweeps of blocks*threads*4 == n4 exactly
  spike_silu_kernel<<<blocks, threads, 0, stream>>>(in, out, n4);
}